// Round 9
// baseline (96.156 us; speedup 1.0000x reference)
//
#include <hip/hip_runtime.h>

// ---------------------------------------------------------------------------
// PAM module: [prep weights] -> fused conv3x3s2+qkv (bf16 MFMA implicit GEMM)
// -> flash attention (16q/wave, block-shared LDS KV staging, static softmax
// P=2^s', shuffle-based PV redistribution, key-split x2 + additive merge)
// -> merge -> bilinear upsample + residual.
// Shapes: x[8][64][128][128] f32, pooled h=w=64 -> N=4096, d_qk=32, d_v=64.
// ---------------------------------------------------------------------------

typedef __attribute__((ext_vector_type(8))) short bf16x8;   // 8 bf16 (4 VGPRs)
typedef __attribute__((ext_vector_type(4))) float f32x4;

#define DEV static __device__ __forceinline__

DEV unsigned f2bf(float f) {                  // RNE f32 -> bf16 bits
  union { float f; unsigned u; } a; a.f = f;
  return (a.u + 0x7FFFu + ((a.u >> 16) & 1u)) >> 16;
}
DEV unsigned cvtpk(float lo, float hi) {      // v_cvt_pk_bf16_f32 (RNE, 1 instr)
  unsigned r;
  asm("v_cvt_pk_bf16_f32 %0, %1, %2" : "=v"(r) : "v"(lo), "v"(hi));
  return r;
}
DEV bf16x8 mk_bf16x8(unsigned w0, unsigned w1, unsigned w2, unsigned w3) {
  union { unsigned u[4]; bf16x8 v; } x;
  x.u[0] = w0; x.u[1] = w1; x.u[2] = w2; x.u[3] = w3;
  return x.v;
}
DEV void gload_lds16(const void* g, void* l) {
  __builtin_amdgcn_global_load_lds(
      (const __attribute__((address_space(1))) void*)g,
      (__attribute__((address_space(3))) void*)l, 16, 0, 0);
}

// ---------------------------------------------------------------------------
// Kernel 0: weight prep.  Ag[oc][k=tap*64+ic] bf16 (conv A-operand, K=576);
// A2g[row][ic] bf16 (rows 0-31 q_w*log2e, 32-63 k_w, 64-127 v_w); bias2[128].
// ---------------------------------------------------------------------------
__global__ __launch_bounds__(256) void prep_kernel(
    const float* __restrict__ pw, const float* __restrict__ qw,
    const float* __restrict__ kw, const float* __restrict__ vw,
    const float* __restrict__ qb, const float* __restrict__ kb,
    const float* __restrict__ vb,
    unsigned short* __restrict__ Ag, unsigned short* __restrict__ A2g,
    float* __restrict__ bias2) {
  const float LOG2E = 1.4426950408889634f;
  const int i = blockIdx.x * 256 + threadIdx.x;
  if (i < 36864) {
    const int oc = i / 576, k = i - oc * 576;
    const int tap = k >> 6, ic = k & 63;
    Ag[i] = (unsigned short)f2bf(pw[(oc * 64 + ic) * 9 + tap]);
  }
  const int j = i - 36864;
  if (j >= 0 && j < 8192) {
    const int r = j >> 6, c = j & 63;
    if (r < 32)       A2g[j] = (unsigned short)f2bf(qw[r * 64 + c] * LOG2E);
    else if (r < 64)  A2g[j] = (unsigned short)f2bf(kw[(r - 32) * 64 + c]);
    else              A2g[j] = (unsigned short)f2bf(vw[(r - 64) * 64 + c]);
  }
  if (j >= 8192 && j < 8320) {
    const int r = j - 8192;
    bias2[r] = r < 32 ? qb[r] * LOG2E : (r < 64 ? kb[r - 32] : vb[r - 64]);
  }
}

// ---------------------------------------------------------------------------
// Kernel 1: fused conv3x3s2 + qkv, bf16 MFMA 16x16x32 (round-2 verified).
// ---------------------------------------------------------------------------
__global__ __launch_bounds__(256) void convqkv_kernel(
    const float* __restrict__ x, const unsigned short* __restrict__ Ag,
    const float* __restrict__ pool_b, const unsigned short* __restrict__ A2g,
    const float* __restrict__ bias2,
    unsigned short* __restrict__ qT, unsigned short* __restrict__ kT,
    unsigned short* __restrict__ vM) {
  const int b = blockIdx.x >> 6, oy = blockIdx.x & 63;
  const int t = threadIdx.x, w = t >> 6, lane = t & 63;
  const int lr = lane & 15, lg = lane >> 4;
  __shared__ unsigned short sIn[390 * 64];   // 48.75 KB, swizzled bytes
  __shared__ unsigned short sXP[64 * 64];    // 8 KB, swizzled bytes
  char* sInB = (char*)sIn;
  char* sXPB = (char*)sXP;

  bf16x8 af[18];
  {
    const unsigned short* ap = Ag + (w * 16 + lr) * 576 + (lg << 3);
    #pragma unroll
    for (int kc = 0; kc < 18; ++kc)
      af[kc] = *(const bf16x8*)(ap + kc * 32);
  }

  #pragma unroll
  for (int rr = 0; rr < 2; ++rr) {
    const int pos = t + rr * 256;
    if (pos < 390) {
      const int ky = pos / 130, xi = pos - ky * 130;
      const int iy = 2 * oy + ky - 1, ix = xi - 1;
      const bool ok = (iy >= 0) & (iy < 128) & (ix >= 0) & (ix < 128);
      const float* xs = x + ((size_t)(b * 64) * 128 + (ok ? iy : 0)) * 128 +
                        (ok ? ix : 0);
      const int sw = pos & 7;
      #pragma unroll
      for (int o = 0; o < 8; ++o) {
        float f[8];
        #pragma unroll
        for (int jj = 0; jj < 8; ++jj)
          f[jj] = ok ? xs[(size_t)(o * 8 + jj) * 16384] : 0.f;
        bf16x8 v = mk_bf16x8(cvtpk(f[0], f[1]), cvtpk(f[2], f[3]),
                             cvtpk(f[4], f[5]), cvtpk(f[6], f[7]));
        *(bf16x8*)(sInB + pos * 128 + ((o ^ sw) << 4)) = v;
      }
    }
  }
  __syncthreads();

  f32x4 acc[4];
  #pragma unroll
  for (int nt = 0; nt < 4; ++nt) acc[nt] = (f32x4){0.f, 0.f, 0.f, 0.f};
  #pragma unroll
  for (int kc = 0; kc < 18; ++kc) {
    const int tap = kc >> 1, ky = tap / 3, kx = tap - ky * 3;
    const int o = ((kc & 1) << 2) + lg;
    #pragma unroll
    for (int nt = 0; nt < 4; ++nt) {
      const int xi = 2 * (nt * 16 + lr) + kx;
      const int pos = ky * 130 + xi;
      bf16x8 bfr = *(const bf16x8*)(sInB + pos * 128 + ((o ^ (pos & 7)) << 4));
      acc[nt] = __builtin_amdgcn_mfma_f32_16x16x32_bf16(af[kc], bfr, acc[nt],
                                                        0, 0, 0);
    }
  }

  const int ocBase = w * 16 + (lg << 2);
  float pb[4];
  #pragma unroll
  for (int r = 0; r < 4; ++r) pb[r] = pool_b[ocBase + r];
  const int ocOct = ocBase >> 3;
  const int withinB = (ocBase & 7) * 2;
  #pragma unroll
  for (int nt = 0; nt < 4; ++nt) {
    const int pos = nt * 16 + lr;
    const unsigned p01 = cvtpk(acc[nt][0] + pb[0], acc[nt][1] + pb[1]);
    const unsigned p23 = cvtpk(acc[nt][2] + pb[2], acc[nt][3] + pb[3]);
    char* base = sXPB + pos * 128 + ((ocOct ^ (pos & 7)) << 4) + withinB;
    *(unsigned*)(base) = p01;
    *(unsigned*)(base + 4) = p23;
  }
  __syncthreads();

  bf16x8 a2[2][2];
  #pragma unroll
  for (int mt = 0; mt < 2; ++mt)
    #pragma unroll
    for (int kc2 = 0; kc2 < 2; ++kc2)
      a2[mt][kc2] = *(const bf16x8*)(A2g + ((2 * w + mt) * 16 + lr) * 64 +
                                     kc2 * 32 + (lg << 3));
  f32x4 acc2[2][4];
  #pragma unroll
  for (int mt = 0; mt < 2; ++mt)
    #pragma unroll
    for (int nt = 0; nt < 4; ++nt) acc2[mt][nt] = (f32x4){0.f, 0.f, 0.f, 0.f};
  #pragma unroll
  for (int kc2 = 0; kc2 < 2; ++kc2) {
    const int o2 = (kc2 << 2) + lg;
    #pragma unroll
    for (int nt = 0; nt < 4; ++nt) {
      const int pos = nt * 16 + lr;
      bf16x8 bfr = *(const bf16x8*)(sXPB + pos * 128 + ((o2 ^ (pos & 7)) << 4));
      acc2[0][nt] = __builtin_amdgcn_mfma_f32_16x16x32_bf16(a2[0][kc2], bfr,
                                                            acc2[0][nt], 0, 0, 0);
      acc2[1][nt] = __builtin_amdgcn_mfma_f32_16x16x32_bf16(a2[1][kc2], bfr,
                                                            acc2[1][nt], 0, 0, 0);
    }
  }

  const int n0g = oy << 6;
  #pragma unroll
  for (int mt = 0; mt < 2; ++mt) {
    const int rowB = (2 * w + mt) * 16 + (lg << 2);
    float b2[4];
    #pragma unroll
    for (int r = 0; r < 4; ++r) b2[r] = bias2[rowB + r];
    if (rowB < 32) {
      #pragma unroll
      for (int nt = 0; nt < 4; ++nt) {
        const int n = n0g + nt * 16 + lr;
        unsigned* dst = (unsigned*)(qT + (((size_t)(b << 12) + n) << 5) + rowB);
        dst[0] = cvtpk(acc2[mt][nt][0] + b2[0], acc2[mt][nt][1] + b2[1]);
        dst[1] = cvtpk(acc2[mt][nt][2] + b2[2], acc2[mt][nt][3] + b2[3]);
      }
    } else if (rowB < 64) {
      #pragma unroll
      for (int nt = 0; nt < 4; ++nt) {
        const int n = n0g + nt * 16 + lr;
        unsigned* dst = (unsigned*)(kT + (((size_t)(b << 12) + n) << 5) + rowB - 32);
        dst[0] = cvtpk(acc2[mt][nt][0] + b2[0], acc2[mt][nt][1] + b2[1]);
        dst[1] = cvtpk(acc2[mt][nt][2] + b2[2], acc2[mt][nt][3] + b2[3]);
      }
    } else {
      const int cv = rowB - 64;
      #pragma unroll
      for (int nt = 0; nt < 4; ++nt) {
        const int n = n0g + nt * 16 + lr;
        #pragma unroll
        for (int r = 0; r < 4; ++r)
          vM[(((size_t)(b << 6) + cv + r) << 12) + n] =
              (unsigned short)f2bf(acc2[mt][nt][r] + b2[r]);
      }
    }
  }
}

// ---------------------------------------------------------------------------
// Kernel 2: flash attention v8 (16 q/wave, shuffle PV, high occupancy).
// Grid 1024 = (b = blk&7 [XCD pin], u = (blk>>3)&63 [64-query tile],
//              split = blk>>9 [keys split*2048..+2047]).
// Block: 4 waves, wave w owns queries u*64+w*16..+15; 32 chunks of 64 keys
// shared via LDS (global_load_lds, LINEAR planes: K [seg 4][key 64] 16B
// units, V [seg 8][c 64]; wave-uniform dests).  Static softmax (P=2^s').
// PV P-redistribution via round-2-verified __shfl + hi-select (no P LDS ->
// 24.5 KB/block -> 4+ blocks/CU).  Partials merged by merge_kernel.
// ---------------------------------------------------------------------------
__global__ __launch_bounds__(256, 4) void attn_kernel(
    const unsigned short* __restrict__ qT, const unsigned short* __restrict__ kT,
    const unsigned short* __restrict__ vM,
    float* __restrict__ attnP, float* __restrict__ Lbuf) {
  __shared__ char lds[24576];           // 2 bufs x (K 4KB | V 8KB)
  const int t = threadIdx.x, w = t >> 6, lane = t & 63;
  const int lr = lane & 15, lg = lane >> 4;
  const int b = blockIdx.x & 7;
  const int u = (blockIdx.x >> 3) & 63;
  const int split = blockIdx.x >> 9;
  const int n0 = (u << 6) + (w << 4);   // this wave's 16 queries
  const int kb0 = split << 11;

  // Q B-frag: queries n0+lr, all 32 channels (k = 8lg+i)
  const unsigned short* qp = qT + (((size_t)(b << 12) + n0 + lr) << 5) + (lg << 3);
  const bf16x8 bq = *(const bf16x8*)(qp);

  // staging source bases
  const unsigned short* ksrc = kT + ((size_t)(b << 12) << 5);          // [key][32]
  const unsigned short* vsrc = vM + (((size_t)(b << 6) + lane) << 12); // row=lane

  f32x4 acc[4];
  #pragma unroll
  for (int j = 0; j < 4; ++j) acc[j] = (f32x4){0.f, 0.f, 0.f, 0.f};
  float l_run = 0.f;

  // PV shuffle constants (round-2 verified slot mapping)
  const int s0 = lr + ((lane & 16) << 1);   // lr + 32*(lg&1)
  const int s1 = s0 + 16;
  const bool hi = (lane & 32) != 0;

  // stage 64-key chunk at kb_ into buffer buf_ (each wave: 1 K + 2 V calls)
  // K plane j=w: unit = j*64+key(=lane); src = K[kb_+lane][d 8w..+7]
  // V planes k=2w,2w+1: unit = k*64+c(=lane); src = V[c=lane][kb_+8k..+7]
  #define STAGE(kb_, buf_) {                                                   \
    char* sb = lds + (buf_) * 12288;                                           \
    gload_lds16((const void*)(ksrc + (((size_t)(kb_) + lane) << 5) + (w << 3)),\
                sb + (w << 10));                                               \
    gload_lds16((const void*)(vsrc + (kb_) + (w << 4)),                        \
                sb + 4096 + (w << 11));                                        \
    gload_lds16((const void*)(vsrc + (kb_) + (w << 4) + 8),                    \
                sb + 4096 + (w << 11) + 1024);                                 \
  }

  STAGE(kb0, 0);
  __syncthreads();
  int buf = 0;

  for (int cc = 0; cc < 32; ++cc) {
    if (cc < 31) STAGE(kb0 + ((cc + 1) << 6), buf ^ 1);
    char* base = lds + buf * 12288;

    // ---- QK^T: A-frag K[key 16j+lr][d 8lg..+7] from plane lg
    f32x4 st[4];
    const f32x4 z4 = {0.f, 0.f, 0.f, 0.f};
    __builtin_amdgcn_s_setprio(1);
    #pragma unroll
    for (int j = 0; j < 4; ++j) {
      const bf16x8 ka =
          *(const bf16x8*)(base + (((lg << 6) + (j << 4) + lr) << 4));
      st[j] = __builtin_amdgcn_mfma_f32_16x16x32_bf16(ka, bq, z4, 0, 0, 0);
    }
    __builtin_amdgcn_s_setprio(0);

    // ---- static softmax numerator: P = 2^s (q pre-scaled by log2e)
    unsigned pw_[4][2];
    {
      float ps0 = 0.f, ps1 = 0.f;
      #pragma unroll
      for (int j = 0; j < 4; ++j) {
        const float p0 = __builtin_amdgcn_exp2f(st[j][0]);
        const float p1 = __builtin_amdgcn_exp2f(st[j][1]);
        const float p2 = __builtin_amdgcn_exp2f(st[j][2]);
        const float p3 = __builtin_amdgcn_exp2f(st[j][3]);
        ps0 += p0 + p1;
        ps1 += p2 + p3;
        pw_[j][0] = cvtpk(p0, p1);
        pw_[j][1] = cvtpk(p2, p3);
      }
      l_run += ps0 + ps1;
    }

    // ---- PV: B-frag from shuffles (round-2 verified), A-frag V from LDS
    #pragma unroll
    for (int h = 0; h < 2; ++h) {
      const int f0 = 2 * h, f1 = 2 * h + 1;
      const unsigned a0 = __shfl((int)pw_[f0][0], s0, 64);
      const unsigned a1 = __shfl((int)pw_[f0][1], s0, 64);
      const unsigned a2 = __shfl((int)pw_[f0][0], s1, 64);
      const unsigned a3 = __shfl((int)pw_[f0][1], s1, 64);
      const unsigned c0 = __shfl((int)pw_[f1][0], s0, 64);
      const unsigned c1 = __shfl((int)pw_[f1][1], s0, 64);
      const unsigned c2 = __shfl((int)pw_[f1][0], s1, 64);
      const unsigned c3 = __shfl((int)pw_[f1][1], s1, 64);
      const bf16x8 pb = hi ? mk_bf16x8(c0, c1, c2, c3)
                           : mk_bf16x8(a0, a1, a2, a3);
      __builtin_amdgcn_s_setprio(1);
      #pragma unroll
      for (int ct = 0; ct < 4; ++ct) {
        const bf16x8 va = *(const bf16x8*)(
            base + 4096 + (((((h << 2) + lg) << 6) + (ct << 4) + lr) << 4));
        acc[ct] = __builtin_amdgcn_mfma_f32_16x16x32_bf16(va, pb, acc[ct],
                                                          0, 0, 0);
      }
      __builtin_amdgcn_s_setprio(0);
    }
    __syncthreads();   // drains vmcnt (stage of buf^1 done) + lgkm; buf reusable
    buf ^= 1;
  }

  // ---- deferred l reduction
  l_run += __shfl_xor(l_run, 16, 64);
  l_run += __shfl_xor(l_run, 32, 64);

  // ---- write raw partial numerators + L (merged later; static softmax sums)
  float* dstP = attnP + ((size_t)split << 21);
  const int q = n0 + lr;
  #pragma unroll
  for (int ct = 0; ct < 4; ++ct)
    #pragma unroll
    for (int r = 0; r < 4; ++r) {
      const int c = (ct << 4) + (lg << 2) + r;
      dstP[((size_t)((b << 6) + c) << 12) + q] = acc[ct][r];
    }
  if (lane < 16)
    Lbuf[((size_t)(split * 8 + b) << 12) + n0 + lane] = l_run;
}

// ---------------------------------------------------------------------------
// Kernel 2b: merge key-splits (in-place into attnP split 0):
// out = (P0 + P1) * gamma / (L0 + L1).
// ---------------------------------------------------------------------------
__global__ __launch_bounds__(256) void merge_kernel(
    float* __restrict__ attnP, const float* __restrict__ Lbuf,
    const float* __restrict__ gamma_p) {
  const int idx = blockIdx.x * 256 + threadIdx.x;   // 524288 threads x f32x4
  const size_t base4 = (size_t)idx << 2;
  const int n4 = (int)(base4 & 4095);
  const int b = (int)(base4 >> 18);                 // (base4>>12)>>6
  const f32x4 p0 = *(const f32x4*)(attnP + base4);
  const f32x4 p1 = *(const f32x4*)(attnP + (1u << 21) + base4);
  const f32x4 l0 = *(const f32x4*)(Lbuf + ((size_t)b << 12) + n4);
  const f32x4 l1 = *(const f32x4*)(Lbuf + ((size_t)(8 + b) << 12) + n4);
  const float g = gamma_p[0];
  f32x4 o;
  #pragma unroll
  for (int i = 0; i < 4; ++i) o[i] = (p0[i] + p1[i]) * g / (l0[i] + l1[i]);
  *(f32x4*)(attnP + base4) = o;
}

// ---------------------------------------------------------------------------
// Kernel 3: bilinear upsample 64->128 (align_corners=True) + residual add.
// ---------------------------------------------------------------------------
__global__ __launch_bounds__(256) void upsample_residual_kernel(
    const float* __restrict__ attn_out, const float* __restrict__ x,
    float* __restrict__ out) {
  const int idx = blockIdx.x * 256 + threadIdx.x;   // 2^21 total
  const int X0 = (idx & 31) << 2;
  int rem = idx >> 5;
  const int Y = rem & 127; rem >>= 7;
  const int c = rem & 63;
  const int b = rem >> 6;

  const float sr = 63.0f / 127.0f;
  float fy = Y * sr;
  int iy = (int)fy; if (iy > 62) iy = 62;
  const float ty = fy - (float)iy;
  const float* ap = attn_out + (((size_t)(b * 64 + c)) << 12);
  const float* r0 = ap + iy * 64;
  const float* r1 = r0 + 64;

  float tmp[4];
  #pragma unroll
  for (int k = 0; k < 4; ++k) {
    const int X = X0 + k;
    float fx = X * sr;
    int ix = (int)fx; if (ix > 62) ix = 62;
    const float tx = fx - (float)ix;
    float v0 = r0[ix] + tx * (r0[ix + 1] - r0[ix]);
    float v1 = r1[ix] + tx * (r1[ix + 1] - r1[ix]);
    tmp[k] = v0 + ty * (v1 - v0);
  }
  const size_t o = (((size_t)((b * 64 + c) * 128 + Y)) << 7) + X0;
  f32x4 xv = *reinterpret_cast<const f32x4*>(x + o);
  f32x4 ov = {tmp[0] + xv[0], tmp[1] + xv[1], tmp[2] + xv[2], tmp[3] + xv[3]};
  *reinterpret_cast<f32x4*>(out + o) = ov;
}

// ---------------------------------------------------------------------------
extern "C" void kernel_launch(void* const* d_in, const int* in_sizes, int n_in,
                              void* d_out, int out_size, void* d_ws, size_t ws_size,
                              hipStream_t stream) {
  const float* x      = (const float*)d_in[0];
  const float* pool_w = (const float*)d_in[1];
  const float* pool_b = (const float*)d_in[2];
  const float* q_w    = (const float*)d_in[3];
  const float* q_b    = (const float*)d_in[4];
  const float* k_w    = (const float*)d_in[5];
  const float* k_b    = (const float*)d_in[6];
  const float* v_w    = (const float*)d_in[7];
  const float* v_b    = (const float*)d_in[8];
  const float* gamma  = (const float*)d_in[9];
  float* out = (float*)d_out;

  char* ws = (char*)d_ws;
  unsigned short* Ag   = (unsigned short*)(ws);             // 73,728 B
  unsigned short* A2g  = (unsigned short*)(ws + 81920);     // 16,384 B
  float* bias2         = (float*)(ws + 98304);              // 512 B
  unsigned short* qT   = (unsigned short*)(ws + 1048576);   // 2 MiB
  unsigned short* kT   = (unsigned short*)(ws + 3145728);   // 2 MiB
  unsigned short* vM   = (unsigned short*)(ws + 5242880);   // 4 MiB
  float* attnP         = (float*)(ws + 9437184);            // 2 x 8 MiB splits
  float* Lbuf          = (float*)(ws + 26214400);           // 2x8x4096 f32=256KB

  prep_kernel<<<177, 256, 0, stream>>>(pool_w, q_w, k_w, v_w, q_b, k_b, v_b,
                                       Ag, A2g, bias2);
  convqkv_kernel<<<512, 256, 0, stream>>>(x, Ag, pool_b, A2g, bias2, qT, kT, vM);
  attn_kernel<<<1024, 256, 0, stream>>>(qT, kT, vM, attnP, Lbuf);
  merge_kernel<<<2048, 256, 0, stream>>>(attnP, Lbuf, gamma);
  upsample_residual_kernel<<<8192, 256, 0, stream>>>(attnP, x, out);
}